// Round 4
// baseline (5669.457 us; speedup 1.0000x reference)
//
#include <hip/hip_runtime.h>
#include <stdint.h>

// ---------------- problem constants ----------------
#define Bb    4
#define Tt    4096
#define DM    512
#define DIN_  1024
#define BT_   16384        // Bb*Tt
#define NW    31           // entropy windows: (4096-256)/128+1
#define DSTATE_ 16

typedef float f32x4 __attribute__((ext_vector_type(4)));
typedef short s16x8 __attribute__((ext_vector_type(8)));

static __device__ __forceinline__ float bf2f(unsigned short h){
  union { unsigned int u; float f; } v; v.u = ((unsigned int)h)<<16; return v.f;
}
static __device__ __forceinline__ unsigned short f2bf(float f){
  union { float f; unsigned int u; } v; v.f = f;
  unsigned int u = v.u + 0x7fffu + ((v.u>>16)&1u);   // RTNE
  return (unsigned short)(u>>16);
}
static __device__ __forceinline__ float gelu_f(float x){
  return 0.5f*x*(1.0f+erff(x*0.7071067811865476f));
}
// async global->LDS, 16B per lane; LDS dest must be lane-linear (base + lane*16)
static __device__ __forceinline__ void gload_lds16(const unsigned short* g, unsigned short* l){
  __builtin_amdgcn_global_load_lds(
      (const __attribute__((address_space(1))) unsigned int*)g,
      (__attribute__((address_space(3))) unsigned int*)l, 16, 0, 0);
}

__global__ void diag_k(float* out, float v){ out[0] = v; }

// ---------------- LayerNorm: 64-token tiles -> xnT (f32 transposed) + xnH (bf16 row-major) ----------------
__global__ __launch_bounds__(256)
void ln_kernel(const float* __restrict__ x, const float* __restrict__ g,
               const float* __restrict__ be, float* __restrict__ xnT,
               unsigned short* __restrict__ xnH)
{
  __shared__ float mrs[64][2];
  __shared__ __align__(16) float tile[64][33];
  int tid = threadIdx.x, lane = tid&63, wv = tid>>6;
  int r0 = blockIdx.x*64;
  // phase 1: per-token mean / rsqrt(var); wave wv handles 16 tokens
  for (int j=0;j<16;j++){
    int r = r0 + wv*16 + j;
    const float4* px = (const float4*)(x + (size_t)r*DM);
    float4 a = px[lane*2], b4 = px[lane*2+1];
    float s1 = a.x+a.y+a.z+a.w + b4.x+b4.y+b4.z+b4.w;
    float s2 = a.x*a.x+a.y*a.y+a.z*a.z+a.w*a.w + b4.x*b4.x+b4.y*b4.y+b4.z*b4.z+b4.w*b4.w;
    #pragma unroll
    for (int o=32;o>=1;o>>=1){ s1 += __shfl_xor(s1,o); s2 += __shfl_xor(s2,o); }
    if (lane==0){
      float m = s1*(1.f/DM);
      float var = s2*(1.f/DM) - m*m;
      mrs[wv*16+j][0] = m;
      mrs[wv*16+j][1] = rsqrtf(var + 1e-5f);
    }
  }
  __syncthreads();
  // phase 2: normalize + write xnH (row-major) and xnT (transposed) via LDS tile
  for (int d0=0; d0<DM; d0+=32){
    #pragma unroll
    for (int q=0;q<8;q++){
      int tk = q*8 + (tid>>5);
      int dj = tid & 31;
      int r = r0+tk, d = d0+dj;
      float v = x[(size_t)r*DM + d];
      float nv = (v - mrs[tk][0])*mrs[tk][1]*g[d] + be[d];
      tile[tk][dj] = nv;
      xnH[(size_t)r*DM + d] = f2bf(nv);
    }
    __syncthreads();
    #pragma unroll
    for (int q=0;q<8;q++){
      int dj = q*4 + (tid>>6);
      int tk = tid & 63;
      xnT[(size_t)(d0+dj)*BT_ + r0 + tk] = tile[tk][dj];
    }
    __syncthreads();
  }
}

// ---------------- weight transpose + f32->bf16: (E,K,N) -> (E,Npad,K) ----------------
__global__ __launch_bounds__(256)
void transpose_cvt(const float* __restrict__ src, unsigned short* __restrict__ dst,
                   int K, int N, int Npad)
{
  __shared__ float tile[32][33];
  int e = blockIdx.z;
  int n0 = blockIdx.x<<5, k0 = blockIdx.y<<5;
  int tx = threadIdx.x & 31, ty = threadIdx.x >> 5;
  #pragma unroll
  for (int i=0;i<4;i++){
    int k = k0 + ty + i*8, n = n0 + tx;
    float v = (n < N) ? src[((size_t)e*K + k)*N + n] : 0.f;
    tile[ty+i*8][tx] = v;
  }
  __syncthreads();
  #pragma unroll
  for (int i=0;i<4;i++){
    int n = n0 + ty + i*8, k = k0 + tx;
    if (n < Npad) dst[((size_t)e*Npad + n)*K + k] = f2bf(tile[tx][ty+i*8]);
  }
}

// ---------------- spectral entropy: partial-sum DFT, one wave per (b,w,d) ----------------
// n = 4m+j factorization: both bins (k, k+64) share partials Pr_j/Pi_j over 4mθ.
__global__ __launch_bounds__(64)
void entropy_kernel(const float* __restrict__ xnT, float* __restrict__ ent_partial)
{
  __shared__ __align__(16) float smp[256];
  int tid = threadIdx.x;
  int blk = blockIdx.x;
  int d = blk & 511;
  int rem = blk >> 9;
  int w = rem % NW;
  int b = rem / NW;
  const float* src = xnT + (size_t)d*BT_ + ((size_t)b<<12) + (size_t)w*128;
  float lsum = 0.f;
  #pragma unroll
  for (int i=0;i<4;i++){
    int n = tid + i*64;
    float v = src[n];
    smp[n] = v; lsum += v;
  }
  __syncthreads();
  #pragma unroll
  for (int o=32;o>=1;o>>=1) lsum += __shfl_xor(lsum,o);

  float th = 6.283185307179586f * (float)(tid+1) / 256.f;
  float c1, s1; sincosf(th, &s1, &c1);
  float c2 = c1*c1 - s1*s1, s2 = 2.f*c1*s1;
  float c4 = c2*c2 - s2*s2, s4 = 2.f*c2*s2;
  float c = 1.f, s = 0.f;
  float Pr0=0,Pr1=0,Pr2=0,Pr3=0, Pi0=0,Pi1=0,Pi2=0,Pi3=0;
  #pragma unroll 4
  for (int m=0;m<64;m++){
    float4 xq = *(const float4*)&smp[m*4];
    Pr0 += xq.x*c; Pi0 += xq.x*s;
    Pr1 += xq.y*c; Pi1 += xq.y*s;
    Pr2 += xq.z*c; Pi2 += xq.z*s;
    Pr3 += xq.w*c; Pi3 += xq.w*s;
    float cn = c*c4 - s*s4; s = s*c4 + c*s4; c = cn;
  }
  float c3 = c1*c2 - s1*s2, s3 = s1*c2 + c1*s2;
  // bin1 (k): j-phase (cj,sj)
  float Re1 = Pr0 + c1*Pr1 - s1*Pi1 + c2*Pr2 - s2*Pi2 + c3*Pr3 - s3*Pi3;
  float Im1 = Pi0 + s1*Pr1 + c1*Pi1 + s2*Pr2 + c2*Pi2 + s3*Pr3 + c3*Pi3;
  // bin2 (k+64): j-phase rotated by i^j: j1->(-s1,c1), j2->(-c2,-s2), j3->(s3,-c3)
  float Re2 = Pr0 - s1*Pr1 - c1*Pi1 - c2*Pr2 + s2*Pi2 + s3*Pr3 + c3*Pi3;
  float Im2 = Pi0 + c1*Pr1 - s1*Pi1 - s2*Pr2 - c2*Pi2 - c3*Pr3 + s3*Pi3;

  float mag[3];
  mag[0] = sqrtf(Re1*Re1+Im1*Im1) + 1e-10f;
  mag[1] = sqrtf(Re2*Re2+Im2*Im2) + 1e-10f;
  mag[2] = fabsf(lsum) + 1e-10f;              // bin 0 (lane 0 only)
  int nb = (tid==0)?3:2;
  float ps = 0.f;
  for (int q=0;q<nb;q++) ps += mag[q];
  #pragma unroll
  for (int o=32;o>=1;o>>=1) ps += __shfl_xor(ps,o);
  float inv = 1.f/ps;
  float es = 0.f;
  for (int q=0;q<nb;q++){ float p = mag[q]*inv; es -= p*logf(p+1e-10f); }
  #pragma unroll
  for (int o=32;o>=1;o>>=1) es += __shfl_xor(es,o);
  if (tid==0) atomicAdd(&ent_partial[b*NW+w], es*(1.f/4.859812404361672f)); // /ln(129)
}

// ---------------- gating: 64-token tiles, coalesced xnT reads ----------------
__global__ __launch_bounds__(256)
void gating_kernel(const float* __restrict__ xnT, const float* __restrict__ gw,
                   const float* __restrict__ entw, const float* __restrict__ entb,
                   const float* __restrict__ temp, const float* __restrict__ ent_partial,
                   float* __restrict__ wfull, float* __restrict__ g_tpe, float* __restrict__ g_avg)
{
  __shared__ __align__(16) float accs[4][64][8];
  __shared__ float l_tpe[8], l_avg[8];
  int tid = threadIdx.x, lane = tid&63, wv = tid>>6;
  int r0 = blockIdx.x*64;
  if (tid < 8){ l_tpe[tid]=0.f; l_avg[tid]=0.f; }
  float acc[8];
  #pragma unroll
  for (int e=0;e<8;e++) acc[e]=0.f;
  for (int i=0;i<128;i++){
    int dd = wv*128 + i;
    float xv = xnT[(size_t)dd*BT_ + r0 + lane];
    const float4* g4p = (const float4*)(gw + (size_t)dd*8);
    float4 w0 = g4p[0], w1 = g4p[1];
    acc[0]+=xv*w0.x; acc[1]+=xv*w0.y; acc[2]+=xv*w0.z; acc[3]+=xv*w0.w;
    acc[4]+=xv*w1.x; acc[5]+=xv*w1.y; acc[6]+=xv*w1.z; acc[7]+=xv*w1.w;
  }
  #pragma unroll
  for (int e=0;e<8;e++) accs[wv][lane][e] = acc[e];
  __syncthreads();
  if (wv==0){
    int r = r0 + lane;
    int b = r0 >> 12;
    float ep = 0.f;
    for (int i=0;i<NW;i++) ep += ent_partial[b*NW+i];
    float ent = ep * (1.f/(NW*512.f));
    float lg[8];
    #pragma unroll
    for (int e=0;e<8;e++)
      lg[e] = accs[0][lane][e]+accs[1][lane][e]+accs[2][lane][e]+accs[3][lane][e];
    float invT = 1.f/(fabsf(temp[0])+1e-6f);
    #pragma unroll
    for (int e=0;e<8;e++) lg[e] = (lg[e] + ent*entw[e] + entb[e]) * invT;
    int i0=0; float v0=lg[0];
    #pragma unroll
    for (int e=1;e<8;e++) if (lg[e] > v0){ v0=lg[e]; i0=e; }
    int i1=-1; float v1=-1e30f;
    #pragma unroll
    for (int e=0;e<8;e++) if (e!=i0 && lg[e] > v1){ v1=lg[e]; i1=e; }
    float e1 = expf(v1-v0);
    float rw0 = 1.f/(1.f+e1), rw1 = e1/(1.f+e1);
    float pr[8], se=0.f;
    #pragma unroll
    for (int e=0;e<8;e++){ pr[e]=expf(lg[e]-v0); se+=pr[e]; }
    float ise = 1.f/se;
    #pragma unroll
    for (int e=0;e<8;e++) wfull[(size_t)r*8+e] = (e==i0)?rw0 : ((e==i1)?rw1 : 0.f);
    atomicAdd(&l_tpe[i0],1.f); atomicAdd(&l_tpe[i1],1.f);
    #pragma unroll
    for (int e=0;e<8;e++) atomicAdd(&l_avg[e], pr[e]*ise);
  }
  __syncthreads();
  if (tid < 8){ atomicAdd(&g_tpe[tid], l_tpe[tid]); atomicAdd(&g_avg[tid], l_avg[tid]); }
}

__global__ void aux_kernel(const float* __restrict__ g_tpe, const float* __restrict__ g_avg,
                           float* __restrict__ out)
{
  float a=0.f;
  #pragma unroll
  for (int e=0;e<8;e++) a += (g_tpe[e]*(1.f/BT_)) * (g_avg[e]*(1.f/BT_));
  out[(size_t)BT_*DM] = 8.f*a;
}

// ---------------- depthwise causal convs (8 channels / thread) ----------------
__global__ __launch_bounds__(256)
void dwconv7_gelu(const unsigned short* __restrict__ H1, const float* __restrict__ k7,
                  const float* __restrict__ kb, unsigned short* __restrict__ H2)
{
  size_t gid = (size_t)blockIdx.x*256 + threadIdx.x;   // group of 8 channels
  int dg = (int)(gid & 127);
  size_t row = gid >> 7;
  int t = (int)(row & (Tt-1));
  int d0 = dg*8;
  float acc[8];
  #pragma unroll
  for (int i=0;i<8;i++) acc[i] = kb[d0+i];
  #pragma unroll
  for (int j=0;j<7;j++){
    int off = 6-j;
    if (t - off >= 0){
      union { uint4 v; unsigned short s[8]; } u;
      u.v = *(const uint4*)(H1 + (row-(size_t)off)*DIN_ + d0);
      #pragma unroll
      for (int i=0;i<8;i++) acc[i] += bf2f(u.s[i]) * k7[(size_t)(d0+i)*7+j];
    }
  }
  union { uint4 v; unsigned short s[8]; } o;
  #pragma unroll
  for (int i=0;i<8;i++) o.s[i] = f2bf(gelu_f(acc[i]));
  *(uint4*)(H2 + row*DIN_ + d0) = o.v;
}

__global__ __launch_bounds__(256)
void dwconv4_silu(const unsigned short* __restrict__ U, const float* __restrict__ cw,
                  const float* __restrict__ cb, unsigned short* __restrict__ uH)
{
  size_t gid = (size_t)blockIdx.x*256 + threadIdx.x;
  int dg = (int)(gid & 127);
  size_t row = gid >> 7;
  int t = (int)(row & (Tt-1));
  int d0 = dg*8;
  float acc[8];
  #pragma unroll
  for (int i=0;i<8;i++) acc[i] = cb[d0+i];
  #pragma unroll
  for (int j=0;j<4;j++){
    int off = 3-j;
    if (t - off >= 0){
      union { uint4 v; unsigned short s[8]; } u;
      u.v = *(const uint4*)(U + (row-(size_t)off)*DIN_ + d0);
      #pragma unroll
      for (int i=0;i<8;i++) acc[i] += bf2f(u.s[i]) * cw[(size_t)(d0+i)*4+j];
    }
  }
  union { uint4 v; unsigned short s[8]; } o;
  #pragma unroll
  for (int i=0;i<8;i++){ float v = acc[i]; o.s[i] = f2bf(v/(1.f+expf(-v))); }
  *(uint4*)(uH + row*DIN_ + d0) = o.v;
}

// ---------------- chunk-parallel selective scan with fused delta ----------------
__global__ __launch_bounds__(256)
void scan_k(const float* __restrict__ dbc, const unsigned short* __restrict__ uH,
            const unsigned short* __restrict__ zH,
            const float* __restrict__ dtw, const float* __restrict__ dtb,
            const float* __restrict__ Alog, const float* __restrict__ Dp,
            unsigned short* __restrict__ yH)
{
  int tid = threadIdx.x;
  int blk = blockIdx.x;
  int dblk = blk & 3, chunk = (blk>>2) & 31, b = blk>>7;
  int d = dblk*256 + tid;
  int t0 = chunk*128, t1 = t0+128;
  int t = (t0 >= 64) ? t0-64 : 0;
  float wk[32];
  #pragma unroll
  for (int k=0;k<32;k++) wk[k] = dtw[(size_t)k*DIN_ + d];
  float dtbv = dtb[d];
  float As[DSTATE_];
  bool fastb = true;
  #pragma unroll
  for (int s=0;s<DSTATE_;s++){
    As[s] = -expf(Alog[(size_t)d*DSTATE_+s]);
    if (fabsf(As[s] + (float)(s+1)) > 1e-3f) fastb=false;
  }
  int fast = __all((int)fastb);
  float Dv = Dp[d];
  float h[DSTATE_];
  #pragma unroll
  for (int s=0;s<DSTATE_;s++) h[s]=0.f;
  for (; t<t1; ++t){
    size_t row = ((size_t)b<<12) + t;
    const float* rowp = dbc + row*128;
    float s0 = dtbv;
    #pragma unroll
    for (int k=0;k<32;k++) s0 += rowp[k]*wk[k];
    float dl = (s0 > 20.f) ? s0 : log1pf(expf(s0));
    float u  = bf2f(uH[row*DIN_+d]);
    float Bv[DSTATE_], Cv[DSTATE_];
    const float4* pb = (const float4*)(rowp + 32);
    const float4* pc = (const float4*)(rowp + 48);
    #pragma unroll
    for (int q=0;q<4;q++){
      float4 fb_ = pb[q]; Bv[4*q]=fb_.x; Bv[4*q+1]=fb_.y; Bv[4*q+2]=fb_.z; Bv[4*q+3]=fb_.w;
      float4 fc_ = pc[q]; Cv[4*q]=fc_.x; Cv[4*q+1]=fc_.y; Cv[4*q+2]=fc_.z; Cv[4*q+3]=fc_.w;
    }
    float du = dl*u;
    if (fast){
      float e1 = __expf(-dl);
      float pw = e1;
      #pragma unroll
      for (int s=0;s<DSTATE_;s++){ h[s] = pw*h[s] + du*Bv[s]; pw *= e1; }
    } else {
      #pragma unroll
      for (int s=0;s<DSTATE_;s++){ float a = __expf(dl*As[s]); h[s] = a*h[s] + du*Bv[s]; }
    }
    if (t >= t0){
      float y = 0.f;
      #pragma unroll
      for (int s=0;s<DSTATE_;s++) y += h[s]*Cv[s];
      y += u*Dv;
      float z = bf2f(zH[row*DIN_+d]);
      float sil = z/(1.f+expf(-z));
      yH[row*DIN_+d] = f2bf(y*sil);
    }
  }
}

// ---------------- bf16 MFMA GEMM, 128x128 tile, BK=64, global_load_lds staging ----------------
enum { E_GELU_BF16=0, E_BF16=1, E_F32=2, E_MOE=3 };

template<int EPI>
__global__ __launch_bounds__(256,3)
void gemm_k(const unsigned short* __restrict__ A, int lda,
            const unsigned short* __restrict__ Bm, int ldb,
            int K,
            const float* __restrict__ bias,
            float* __restrict__ oF, unsigned short* __restrict__ oH, int ldo,
            const float* __restrict__ wfull, int ecol,
            const float* __restrict__ resid,
            unsigned short* __restrict__ oH2)
{
  __shared__ unsigned short As[128*64];
  __shared__ unsigned short Bs[128*64];
  int tid = threadIdx.x, lane = tid&63, wv = tid>>6;
  int wm = wv>>1, wn = wv&1;
  // XCD-aware bijective swizzle (all grids have nwg % 8 == 0)
  int nwg = gridDim.x*gridDim.y;
  int wg  = blockIdx.y*gridDim.x + blockIdx.x;
  int cpx = nwg >> 3;
  int swz = (wg & 7)*cpx + (wg >> 3);
  int bx = swz % gridDim.x, by = swz / gridDim.x;
  int mb = by*128, nb = bx*128;
  int g4 = (lane>>4)<<2;
  int r16 = lane & 15;
  // staging coords: wave wv covers rows [wv*32, wv*32+32)
  int srow = wv*32 + (lane>>3);
  int scol = (lane&7)*8;            // shorts
  f32x4 acc[4][4];
  #pragma unroll
  for (int i=0;i<4;i++)
    #pragma unroll
    for (int j=0;j<4;j++) acc[i][j] = (f32x4){0.f,0.f,0.f,0.f};

  for (int k0=0; k0<K; k0+=64) {
    #pragma unroll
    for (int i=0;i<4;i++){
      gload_lds16(A  + (size_t)(mb+srow+i*8)*lda + k0 + scol, &As[(wv*32+i*8)*64 + lane*8]);
      gload_lds16(Bm + (size_t)(nb+srow+i*8)*ldb + k0 + scol, &Bs[(wv*32+i*8)*64 + lane*8]);
    }
    __syncthreads();
    #pragma unroll
    for (int ks=0; ks<2; ks++){
      int kb = ks<<5;
      s16x8 fa[4], fb[4];
      #pragma unroll
      for (int mi=0;mi<4;mi++){
        const unsigned short* p = &As[(wm*64+mi*16+r16)*64 + kb + g4];
        union { uint64_t q[2]; s16x8 v; } u;
        u.q[0] = *(const uint64_t*)p;
        u.q[1] = *(const uint64_t*)(p+16);
        fa[mi] = u.v;
      }
      #pragma unroll
      for (int ni=0;ni<4;ni++){
        const unsigned short* p = &Bs[(wn*64+ni*16+r16)*64 + kb + g4];
        union { uint64_t q[2]; s16x8 v; } u;
        u.q[0] = *(const uint64_t*)p;
        u.q[1] = *(const uint64_t*)(p+16);
        fb[ni] = u.v;
      }
      #pragma unroll
      for (int mi=0;mi<4;mi++)
        #pragma unroll
        for (int ni=0;ni<4;ni++)
          acc[mi][ni] = __builtin_amdgcn_mfma_f32_16x16x32_bf16(fa[mi], fb[ni], acc[mi][ni], 0,0,0);
    }
    __syncthreads();
  }
  #pragma unroll
  for (int mi=0;mi<4;mi++){
    #pragma unroll
    for (int ni=0;ni<4;ni++){
      #pragma unroll
      for (int rr=0;rr<4;rr++){
        int row = mb + wm*64 + mi*16 + g4 + rr;
        int col = nb + wn*64 + ni*16 + r16;
        float v = acc[mi][ni][rr];
        if constexpr (EPI == E_GELU_BF16){
          v += bias[col];
          oH[(size_t)row*ldo + col] = f2bf(gelu_f(v));
        } else if constexpr (EPI == E_BF16){
          if (bias) v += bias[col];
          if (oH2 && col >= 1024) oH2[(size_t)row*1024 + col - 1024] = f2bf(v);
          else                    oH [(size_t)row*ldo  + col] = f2bf(v);
        } else if constexpr (EPI == E_F32){
          oF[(size_t)row*ldo + col] = v;
        } else { // E_MOE
          size_t o = (size_t)row*ldo + col;
          if (bias) v += bias[col];
          float w = wfull[(size_t)row*8 + ecol];
          float base = resid ? resid[o] : oF[o];
          oF[o] = base + w*v;
        }
      }
    }
  }
}

extern "C" void kernel_launch(void* const* d_in, const int* in_sizes, int n_in,
                              void* d_out, int out_size, void* d_ws, size_t ws_size,
                              hipStream_t stream)
{
  (void)in_sizes; (void)n_in; (void)out_size;
  const float* x      = (const float*)d_in[0];
  const float* ln_g   = (const float*)d_in[1];
  const float* ln_b   = (const float*)d_in[2];
  const float* gate_w = (const float*)d_in[3];
  const float* ent_w  = (const float*)d_in[4];
  const float* ent_b  = (const float*)d_in[5];
  const float* temp   = (const float*)d_in[6];
  const float* cin_w  = (const float*)d_in[7];
  const float* cin_b  = (const float*)d_in[8];
  const float* ck     = (const float*)d_in[9];
  const float* ck_b   = (const float*)d_in[10];
  const float* cout_w = (const float*)d_in[11];
  const float* cout_b = (const float*)d_in[12];
  const float* m_in   = (const float*)d_in[13];
  const float* m_cw   = (const float*)d_in[14];
  const float* m_cb   = (const float*)d_in[15];
  const float* m_xp   = (const float*)d_in[16];
  const float* m_dtw  = (const float*)d_in[17];
  const float* m_dtb  = (const float*)d_in[18];
  const float* m_alog = (const float*)d_in[19];
  const float* m_Dd   = (const float*)d_in[20];
  const float* m_op   = (const float*)d_in[21];
  float* out = (float*)d_out;
  char* ws = (char*)d_ws;

  size_t off = 0;
  auto alloc = [&](size_t bytes)->size_t{
    size_t r = off; off += (bytes + 4095) & ~(size_t)4095; return r;
  };
  size_t o_xnH  = alloc((size_t)BT_*DM*2);
  size_t o_wf   = alloc((size_t)BT_*8*4);
  size_t o_st   = alloc(4096);
  size_t o_wCI  = alloc((size_t)4*DIN_*DM*2);
  size_t o_wCO  = alloc((size_t)4*DM*DIN_*2);
  size_t o_wIP  = alloc((size_t)4*2048*DM*2);
  size_t o_wXP  = alloc((size_t)4*128*DIN_*2);
  size_t o_wOP  = alloc((size_t)4*DM*DIN_*2);
  size_t o_A0   = alloc((size_t)BT_*DIN_*2);   // u_raw / conv H1 / y
  size_t o_A1   = alloc((size_t)BT_*DIN_*2);   // z
  size_t o_A3   = alloc((size_t)BT_*DIN_*2);   // u' / conv H2
  size_t o_A4   = alloc((size_t)BT_*128*4);    // dbc f32
  size_t o_xnT  = alloc((size_t)BT_*DM*4);     // f32 xn transposed (DM, BT)
  size_t need = off;

  if (ws_size < need){
    diag_k<<<1,1,0,stream>>>(out, (float)(ws_size >> 20));
    return;
  }

  unsigned short* xnH  = (unsigned short*)(ws + o_xnH);
  float*          xnT  = (float*)(ws + o_xnT);
  float*          wfull= (float*)(ws + o_wf);
  float*          entP = (float*)(ws + o_st);
  float*          gtpe = (float*)(ws + o_st + 512);
  float*          gavg = (float*)(ws + o_st + 544);
  unsigned short* wtCI = (unsigned short*)(ws + o_wCI);
  unsigned short* wtCO = (unsigned short*)(ws + o_wCO);
  unsigned short* wtIP = (unsigned short*)(ws + o_wIP);
  unsigned short* wtXP = (unsigned short*)(ws + o_wXP);
  unsigned short* wtOP = (unsigned short*)(ws + o_wOP);
  unsigned short* a0H  = (unsigned short*)(ws + o_A0);
  unsigned short* a1H  = (unsigned short*)(ws + o_A1);
  unsigned short* a3H  = (unsigned short*)(ws + o_A3);
  float*          a4F  = (float*)(ws + o_A4);

  hipMemsetAsync(ws + o_st, 0, 4096, stream);

  transpose_cvt<<<dim3(32,16,4),256,0,stream>>>(cin_w,  wtCI, 512, 1024, 1024);
  transpose_cvt<<<dim3(16,32,4),256,0,stream>>>(cout_w, wtCO, 1024, 512, 512);
  transpose_cvt<<<dim3(64,16,4),256,0,stream>>>(m_in,   wtIP, 512, 2048, 2048);
  transpose_cvt<<<dim3( 4,32,4),256,0,stream>>>(m_xp,   wtXP, 1024, 64, 128);
  transpose_cvt<<<dim3(16,32,4),256,0,stream>>>(m_op,   wtOP, 1024, 512, 512);

  ln_kernel<<<BT_/64,256,0,stream>>>(x, ln_g, ln_b, xnT, xnH);
  entropy_kernel<<<Bb*NW*512,64,0,stream>>>(xnT, entP);
  gating_kernel<<<BT_/64,256,0,stream>>>(xnT, gate_w, ent_w, ent_b, temp, entP, wfull, gtpe, gavg);

  // conv experts (0..3)
  for (int e=0;e<4;e++){
    gemm_k<E_GELU_BF16><<<dim3(8,128),256,0,stream>>>(
        xnH, DM, wtCI + (size_t)e*DIN_*DM, DM, DM,
        cin_b + (size_t)e*DIN_, nullptr, a0H, DIN_, nullptr, 0, nullptr, nullptr);
    dwconv7_gelu<<<BT_*DIN_/8/256,256,0,stream>>>(a0H, ck + (size_t)e*DIN_*7, ck_b + (size_t)e*DIN_, a3H);
    gemm_k<E_MOE><<<dim3(4,128),256,0,stream>>>(
        a3H, DIN_, wtCO + (size_t)e*DM*DIN_, DIN_, DIN_,
        cout_b + (size_t)e*DM, out, nullptr, DM, wfull, e, (e==0)? x : nullptr, nullptr);
  }

  // mamba experts (4..7)
  for (int e=0;e<4;e++){
    gemm_k<E_BF16><<<dim3(16,128),256,0,stream>>>(
        xnH, DM, wtIP + (size_t)e*2048*DM, DM, DM,
        nullptr, nullptr, a0H, DIN_, nullptr, 0, nullptr, a1H);            // u_raw + z split
    dwconv4_silu<<<BT_*DIN_/8/256,256,0,stream>>>(a0H, m_cw + (size_t)e*DIN_*4, m_cb + (size_t)e*DIN_, a3H);
    gemm_k<E_F32><<<dim3(1,128),256,0,stream>>>(
        a3H, DIN_, wtXP + (size_t)e*128*DIN_, DIN_, DIN_,
        nullptr, a4F, nullptr, 128, nullptr, 0, nullptr, nullptr);         // dbc
    scan_k<<<512,256,0,stream>>>(a4F, a3H, a1H,
        m_dtw + (size_t)e*32*DIN_, m_dtb + (size_t)e*DIN_,
        m_alog + (size_t)e*DIN_*DSTATE_, m_Dd + (size_t)e*DIN_, a0H);      // y -> a0H
    gemm_k<E_MOE><<<dim3(4,128),256,0,stream>>>(
        a0H, DIN_, wtOP + (size_t)e*DM*DIN_, DIN_, DIN_,
        nullptr, out, nullptr, DM, wfull, 4+e, nullptr, nullptr);
  }

  aux_kernel<<<1,1,0,stream>>>(gtpe, gavg, out);
}

// Round 5
// 3738.708 us; speedup vs baseline: 1.5164x; 1.5164x over previous
//
#include <hip/hip_runtime.h>
#include <stdint.h>

// ---------------- problem constants ----------------
#define Bb    4
#define Tt    4096
#define DM    512
#define DIN_  1024
#define BT_   16384        // Bb*Tt
#define NW    31           // entropy windows: (4096-256)/128+1
#define DSTATE_ 16

typedef float f32x4 __attribute__((ext_vector_type(4)));
typedef short s16x8 __attribute__((ext_vector_type(8)));

static __device__ __forceinline__ float bf2f(unsigned short h){
  union { unsigned int u; float f; } v; v.u = ((unsigned int)h)<<16; return v.f;
}
static __device__ __forceinline__ unsigned short f2bf(float f){
  union { float f; unsigned int u; } v; v.f = f;
  unsigned int u = v.u + 0x7fffu + ((v.u>>16)&1u);   // RTNE
  return (unsigned short)(u>>16);
}
static __device__ __forceinline__ float gelu_f(float x){
  return 0.5f*x*(1.0f+erff(x*0.7071067811865476f));
}
// async global->LDS, 16B per lane; LDS dest lane-linear (base + lane*16B)
static __device__ __forceinline__ void gload_lds16(const unsigned short* g, unsigned short* l){
  __builtin_amdgcn_global_load_lds(
      (const __attribute__((address_space(1))) unsigned int*)g,
      (__attribute__((address_space(3))) unsigned int*)l, 16, 0, 0);
}
// swizzled LDS short-index: XOR row low bits into 16B-chunk index (rows spread over banks)
static __device__ __forceinline__ int lds_swz(int row, int col){
  return row*64 + ((((col>>3) ^ row) & 7)<<3) + (col&7);
}

__global__ void diag_k(float* out, float v){ out[0] = v; }

// ---------------- LayerNorm: 64-token tiles -> xnT (f32 transposed) + xnH (bf16 row-major) ----------------
__global__ __launch_bounds__(256)
void ln_kernel(const float* __restrict__ x, const float* __restrict__ g,
               const float* __restrict__ be, float* __restrict__ xnT,
               unsigned short* __restrict__ xnH)
{
  __shared__ float mrs[64][2];
  __shared__ __align__(16) float tile[64][33];
  int tid = threadIdx.x, lane = tid&63, wv = tid>>6;
  int r0 = blockIdx.x*64;
  for (int j=0;j<16;j++){
    int r = r0 + wv*16 + j;
    const float4* px = (const float4*)(x + (size_t)r*DM);
    float4 a = px[lane*2], b4 = px[lane*2+1];
    float s1 = a.x+a.y+a.z+a.w + b4.x+b4.y+b4.z+b4.w;
    float s2 = a.x*a.x+a.y*a.y+a.z*a.z+a.w*a.w + b4.x*b4.x+b4.y*b4.y+b4.z*b4.z+b4.w*b4.w;
    #pragma unroll
    for (int o=32;o>=1;o>>=1){ s1 += __shfl_xor(s1,o); s2 += __shfl_xor(s2,o); }
    if (lane==0){
      float m = s1*(1.f/DM);
      float var = s2*(1.f/DM) - m*m;
      mrs[wv*16+j][0] = m;
      mrs[wv*16+j][1] = rsqrtf(var + 1e-5f);
    }
  }
  __syncthreads();
  for (int d0=0; d0<DM; d0+=32){
    #pragma unroll
    for (int q=0;q<8;q++){
      int tk = q*8 + (tid>>5);
      int dj = tid & 31;
      int r = r0+tk, d = d0+dj;
      float v = x[(size_t)r*DM + d];
      float nv = (v - mrs[tk][0])*mrs[tk][1]*g[d] + be[d];
      tile[tk][dj] = nv;
      xnH[(size_t)r*DM + d] = f2bf(nv);
    }
    __syncthreads();
    #pragma unroll
    for (int q=0;q<8;q++){
      int dj = q*4 + (tid>>6);
      int tk = tid & 63;
      xnT[(size_t)(d0+dj)*BT_ + r0 + tk] = tile[tk][dj];
    }
    __syncthreads();
  }
}

// ---------------- weight transpose + f32->bf16: (E,K,N) -> (E,Npad,K) ----------------
__global__ __launch_bounds__(256)
void transpose_cvt(const float* __restrict__ src, unsigned short* __restrict__ dst,
                   int K, int N, int Npad)
{
  __shared__ float tile[32][33];
  int e = blockIdx.z;
  int n0 = blockIdx.x<<5, k0 = blockIdx.y<<5;
  int tx = threadIdx.x & 31, ty = threadIdx.x >> 5;
  #pragma unroll
  for (int i=0;i<4;i++){
    int k = k0 + ty + i*8, n = n0 + tx;
    float v = (n < N) ? src[((size_t)e*K + k)*N + n] : 0.f;
    tile[ty+i*8][tx] = v;
  }
  __syncthreads();
  #pragma unroll
  for (int i=0;i<4;i++){
    int n = n0 + ty + i*8, k = k0 + tx;
    if (n < Npad) dst[((size_t)e*Npad + n)*K + k] = f2bf(tile[tx][ty+i*8]);
  }
}

// ---------------- spectral entropy: 4 units/block, 2-chain ILP DFT ----------------
__global__ __launch_bounds__(256)
void entropy_kernel(const float* __restrict__ xnT, float* __restrict__ ent_partial)
{
  __shared__ __align__(16) float smp[4][256];
  int tid = threadIdx.x, lane = tid&63, wv = tid>>6;
  int unit = blockIdx.x*4 + wv;
  int d = unit & 511;
  int rem = unit >> 9;
  int w = rem % NW;
  int b = rem / NW;
  const float4* src = (const float4*)(xnT + (size_t)d*BT_ + ((size_t)b<<12) + (size_t)w*128);
  float4 mine = src[lane];
  *(float4*)&smp[wv][lane*4] = mine;
  float lsum = mine.x+mine.y+mine.z+mine.w;
  __syncthreads();
  #pragma unroll
  for (int o=32;o>=1;o>>=1) lsum += __shfl_xor(lsum,o);

  int k = lane + 1;
  float th = 6.283185307179586f * (float)k / 256.f;
  float c1, s1; sincosf(th, &s1, &c1);
  float c2 = c1*c1 - s1*s1, s2 = 2.f*c1*s1;
  float c4 = c2*c2 - s2*s2, s4 = 2.f*c2*s2;
  float ar = (k&1) ? -1.f : 1.f;        // phase of chain 1: e^{i*128θ} = (-1)^k
  float c = 1.f, s = 0.f;
  float Pr[2][4], Pi[2][4];
  #pragma unroll
  for (int cc=0;cc<2;cc++)
    #pragma unroll
    for (int j=0;j<4;j++){ Pr[cc][j]=0.f; Pi[cc][j]=0.f; }
  const float4* s4p = (const float4*)&smp[wv][0];
  #pragma unroll 8
  for (int m=0;m<32;m++){
    float4 x0 = s4p[m];
    float4 x1 = s4p[m+32];
    float tc = ar*c, ts = ar*s;
    Pr[0][0]+=x0.x*c;  Pi[0][0]+=x0.x*s;
    Pr[0][1]+=x0.y*c;  Pi[0][1]+=x0.y*s;
    Pr[0][2]+=x0.z*c;  Pi[0][2]+=x0.z*s;
    Pr[0][3]+=x0.w*c;  Pi[0][3]+=x0.w*s;
    Pr[1][0]+=x1.x*tc; Pi[1][0]+=x1.x*ts;
    Pr[1][1]+=x1.y*tc; Pi[1][1]+=x1.y*ts;
    Pr[1][2]+=x1.z*tc; Pi[1][2]+=x1.z*ts;
    Pr[1][3]+=x1.w*tc; Pi[1][3]+=x1.w*ts;
    float cn = c*c4 - s*s4; s = s*c4 + c*s4; c = cn;
  }
  float Pr0 = Pr[0][0]+Pr[1][0], Pi0 = Pi[0][0]+Pi[1][0];
  float Pr1 = Pr[0][1]+Pr[1][1], Pi1 = Pi[0][1]+Pi[1][1];
  float Pr2 = Pr[0][2]+Pr[1][2], Pi2 = Pi[0][2]+Pi[1][2];
  float Pr3 = Pr[0][3]+Pr[1][3], Pi3 = Pi[0][3]+Pi[1][3];
  float c3 = c1*c2 - s1*s2, s3 = s1*c2 + c1*s2;
  float Re1 = Pr0 + c1*Pr1 - s1*Pi1 + c2*Pr2 - s2*Pi2 + c3*Pr3 - s3*Pi3;
  float Im1 = Pi0 + s1*Pr1 + c1*Pi1 + s2*Pr2 + c2*Pi2 + s3*Pr3 + c3*Pi3;
  float Re2 = Pr0 - s1*Pr1 - c1*Pi1 - c2*Pr2 + s2*Pi2 + s3*Pr3 + c3*Pi3;
  float Im2 = Pi0 + c1*Pr1 - s1*Pi1 - s2*Pr2 - c2*Pi2 - c3*Pr3 + s3*Pi3;

  float mag[3];
  mag[0] = sqrtf(Re1*Re1+Im1*Im1) + 1e-10f;
  mag[1] = sqrtf(Re2*Re2+Im2*Im2) + 1e-10f;
  mag[2] = fabsf(lsum) + 1e-10f;
  int nb = (lane==0)?3:2;
  float ps = 0.f;
  for (int q=0;q<nb;q++) ps += mag[q];
  #pragma unroll
  for (int o=32;o>=1;o>>=1) ps += __shfl_xor(ps,o);
  float inv = 1.f/ps;
  float es = 0.f;
  for (int q=0;q<nb;q++){ float p = mag[q]*inv; es -= p*logf(p+1e-10f); }
  #pragma unroll
  for (int o=32;o>=1;o>>=1) es += __shfl_xor(es,o);
  if (lane==0) atomicAdd(&ent_partial[b*NW+w], es*(1.f/4.859812404361672f)); // /ln(129)
}

// ---------------- gating: 64-token tiles, coalesced xnT reads ----------------
__global__ __launch_bounds__(256)
void gating_kernel(const float* __restrict__ xnT, const float* __restrict__ gw,
                   const float* __restrict__ entw, const float* __restrict__ entb,
                   const float* __restrict__ temp, const float* __restrict__ ent_partial,
                   float* __restrict__ wfull, float* __restrict__ g_tpe, float* __restrict__ g_avg)
{
  __shared__ __align__(16) float accs[4][64][8];
  __shared__ float l_tpe[8], l_avg[8];
  int tid = threadIdx.x, lane = tid&63, wv = tid>>6;
  int r0 = blockIdx.x*64;
  if (tid < 8){ l_tpe[tid]=0.f; l_avg[tid]=0.f; }
  float acc[8];
  #pragma unroll
  for (int e=0;e<8;e++) acc[e]=0.f;
  for (int i=0;i<128;i++){
    int dd = wv*128 + i;
    float xv = xnT[(size_t)dd*BT_ + r0 + lane];
    const float4* g4p = (const float4*)(gw + (size_t)dd*8);
    float4 w0 = g4p[0], w1 = g4p[1];
    acc[0]+=xv*w0.x; acc[1]+=xv*w0.y; acc[2]+=xv*w0.z; acc[3]+=xv*w0.w;
    acc[4]+=xv*w1.x; acc[5]+=xv*w1.y; acc[6]+=xv*w1.z; acc[7]+=xv*w1.w;
  }
  #pragma unroll
  for (int e=0;e<8;e++) accs[wv][lane][e] = acc[e];
  __syncthreads();
  if (wv==0){
    int r = r0 + lane;
    int b = r0 >> 12;
    float ep = 0.f;
    for (int i=0;i<NW;i++) ep += ent_partial[b*NW+i];
    float ent = ep * (1.f/(NW*512.f));
    float lg[8];
    #pragma unroll
    for (int e=0;e<8;e++)
      lg[e] = accs[0][lane][e]+accs[1][lane][e]+accs[2][lane][e]+accs[3][lane][e];
    float invT = 1.f/(fabsf(temp[0])+1e-6f);
    #pragma unroll
    for (int e=0;e<8;e++) lg[e] = (lg[e] + ent*entw[e] + entb[e]) * invT;
    int i0=0; float v0=lg[0];
    #pragma unroll
    for (int e=1;e<8;e++) if (lg[e] > v0){ v0=lg[e]; i0=e; }
    int i1=-1; float v1=-1e30f;
    #pragma unroll
    for (int e=0;e<8;e++) if (e!=i0 && lg[e] > v1){ v1=lg[e]; i1=e; }
    float e1 = expf(v1-v0);
    float rw0 = 1.f/(1.f+e1), rw1 = e1/(1.f+e1);
    float pr[8], se=0.f;
    #pragma unroll
    for (int e=0;e<8;e++){ pr[e]=expf(lg[e]-v0); se+=pr[e]; }
    float ise = 1.f/se;
    #pragma unroll
    for (int e=0;e<8;e++) wfull[(size_t)r*8+e] = (e==i0)?rw0 : ((e==i1)?rw1 : 0.f);
    atomicAdd(&l_tpe[i0],1.f); atomicAdd(&l_tpe[i1],1.f);
    #pragma unroll
    for (int e=0;e<8;e++) atomicAdd(&l_avg[e], pr[e]*ise);
  }
  __syncthreads();
  if (tid < 8){ atomicAdd(&g_tpe[tid], l_tpe[tid]); atomicAdd(&g_avg[tid], l_avg[tid]); }
}

__global__ void aux_kernel(const float* __restrict__ g_tpe, const float* __restrict__ g_avg,
                           float* __restrict__ out)
{
  float a=0.f;
  #pragma unroll
  for (int e=0;e<8;e++) a += (g_tpe[e]*(1.f/BT_)) * (g_avg[e]*(1.f/BT_));
  out[(size_t)BT_*DM] = 8.f*a;
}

// ---------------- depthwise causal convs (8 channels / thread) ----------------
__global__ __launch_bounds__(256)
void dwconv7_gelu(const unsigned short* __restrict__ H1, const float* __restrict__ k7,
                  const float* __restrict__ kb, unsigned short* __restrict__ H2)
{
  size_t gid = (size_t)blockIdx.x*256 + threadIdx.x;
  int dg = (int)(gid & 127);
  size_t row = gid >> 7;
  int t = (int)(row & (Tt-1));
  int d0 = dg*8;
  float acc[8];
  #pragma unroll
  for (int i=0;i<8;i++) acc[i] = kb[d0+i];
  #pragma unroll
  for (int j=0;j<7;j++){
    int off = 6-j;
    if (t - off >= 0){
      union { uint4 v; unsigned short s[8]; } u;
      u.v = *(const uint4*)(H1 + (row-(size_t)off)*DIN_ + d0);
      #pragma unroll
      for (int i=0;i<8;i++) acc[i] += bf2f(u.s[i]) * k7[(size_t)(d0+i)*7+j];
    }
  }
  union { uint4 v; unsigned short s[8]; } o;
  #pragma unroll
  for (int i=0;i<8;i++) o.s[i] = f2bf(gelu_f(acc[i]));
  *(uint4*)(H2 + row*DIN_ + d0) = o.v;
}

__global__ __launch_bounds__(256)
void dwconv4_silu(const unsigned short* __restrict__ U, const float* __restrict__ cw,
                  const float* __restrict__ cb, unsigned short* __restrict__ uH)
{
  size_t gid = (size_t)blockIdx.x*256 + threadIdx.x;
  int dg = (int)(gid & 127);
  size_t row = gid >> 7;
  int t = (int)(row & (Tt-1));
  int d0 = dg*8;
  float acc[8];
  #pragma unroll
  for (int i=0;i<8;i++) acc[i] = cb[d0+i];
  #pragma unroll
  for (int j=0;j<4;j++){
    int off = 3-j;
    if (t - off >= 0){
      union { uint4 v; unsigned short s[8]; } u;
      u.v = *(const uint4*)(U + (row-(size_t)off)*DIN_ + d0);
      #pragma unroll
      for (int i=0;i<8;i++) acc[i] += bf2f(u.s[i]) * cw[(size_t)(d0+i)*4+j];
    }
  }
  union { uint4 v; unsigned short s[8]; } o;
  #pragma unroll
  for (int i=0;i<8;i++){ float v = acc[i]; o.s[i] = f2bf(v/(1.f+expf(-v))); }
  *(uint4*)(uH + row*DIN_ + d0) = o.v;
}

// ---------------- chunk-parallel selective scan with fused delta ----------------
__global__ __launch_bounds__(256)
void scan_k(const float* __restrict__ dbc, const unsigned short* __restrict__ uH,
            const unsigned short* __restrict__ zH,
            const float* __restrict__ dtw, const float* __restrict__ dtb,
            const float* __restrict__ Alog, const float* __restrict__ Dp,
            unsigned short* __restrict__ yH)
{
  int tid = threadIdx.x;
  int blk = blockIdx.x;
  int dblk = blk & 3, chunk = (blk>>2) & 31, b = blk>>7;
  int d = dblk*256 + tid;
  int t0 = chunk*128, t1 = t0+128;
  int t = (t0 >= 64) ? t0-64 : 0;
  float wk[32];
  #pragma unroll
  for (int k=0;k<32;k++) wk[k] = dtw[(size_t)k*DIN_ + d];
  float dtbv = dtb[d];
  float As[DSTATE_];
  bool fastb = true;
  #pragma unroll
  for (int s=0;s<DSTATE_;s++){
    As[s] = -expf(Alog[(size_t)d*DSTATE_+s]);
    if (fabsf(As[s] + (float)(s+1)) > 1e-3f) fastb=false;
  }
  int fast = __all((int)fastb);
  float Dv = Dp[d];
  float h[DSTATE_];
  #pragma unroll
  for (int s=0;s<DSTATE_;s++) h[s]=0.f;
  for (; t<t1; ++t){
    size_t row = ((size_t)b<<12) + t;
    const float* rowp = dbc + row*128;
    float p0=0.f,p1=0.f,p2=0.f,p3=0.f;
    #pragma unroll
    for (int k=0;k<32;k+=4){
      p0 += rowp[k]*wk[k];   p1 += rowp[k+1]*wk[k+1];
      p2 += rowp[k+2]*wk[k+2]; p3 += rowp[k+3]*wk[k+3];
    }
    float s0 = dtbv + ((p0+p1)+(p2+p3));
    float dl = (s0 > 20.f) ? s0 : log1pf(expf(s0));
    float u  = bf2f(uH[row*DIN_+d]);
    float Bv[DSTATE_], Cv[DSTATE_];
    const float4* pb = (const float4*)(rowp + 32);
    const float4* pc = (const float4*)(rowp + 48);
    #pragma unroll
    for (int q=0;q<4;q++){
      float4 fb_ = pb[q]; Bv[4*q]=fb_.x; Bv[4*q+1]=fb_.y; Bv[4*q+2]=fb_.z; Bv[4*q+3]=fb_.w;
      float4 fc_ = pc[q]; Cv[4*q]=fc_.x; Cv[4*q+1]=fc_.y; Cv[4*q+2]=fc_.z; Cv[4*q+3]=fc_.w;
    }
    float du = dl*u;
    if (fast){
      float e1 = __expf(-dl);
      float pw = e1;
      #pragma unroll
      for (int s=0;s<DSTATE_;s++){ h[s] = pw*h[s] + du*Bv[s]; pw *= e1; }
    } else {
      #pragma unroll
      for (int s=0;s<DSTATE_;s++){ float a = __expf(dl*As[s]); h[s] = a*h[s] + du*Bv[s]; }
    }
    if (t >= t0){
      float y = 0.f;
      #pragma unroll
      for (int s=0;s<DSTATE_;s++) y += h[s]*Cv[s];
      y += u*Dv;
      float z = bf2f(zH[row*DIN_+d]);
      float sil = z/(1.f+expf(-z));
      yH[row*DIN_+d] = f2bf(y*sil);
    }
  }
}

// ---------------- bf16 MFMA GEMM: gload_lds staging + both-sides chunk-XOR swizzle ----------------
enum { E_GELU_BF16=0, E_BF16=1, E_F32=2, E_MOE=3 };

template<int EPI>
__global__ __launch_bounds__(256,3)
void gemm_k(const unsigned short* __restrict__ A, int lda,
            const unsigned short* __restrict__ Bm, int ldb,
            int K,
            const float* __restrict__ bias,
            float* __restrict__ oF, unsigned short* __restrict__ oH, int ldo,
            const float* __restrict__ wfull, int ecol,
            const float* __restrict__ resid,
            unsigned short* __restrict__ oH2)
{
  __shared__ unsigned short As[128*64];
  __shared__ unsigned short Bs[128*64];
  int tid = threadIdx.x, lane = tid&63, wv = tid>>6;
  int wm = wv>>1, wn = wv&1;
  // XCD-aware bijective swizzle (all grids have nwg % 8 == 0)
  int nwg = gridDim.x*gridDim.y;
  int wg  = blockIdx.y*gridDim.x + blockIdx.x;
  int cpx = nwg >> 3;
  int swz = (wg & 7)*cpx + (wg >> 3);
  int bx = swz % gridDim.x, by = swz / gridDim.x;
  int mb = by*128, nb = bx*128;
  int g4 = (lane>>4)<<2;
  int r16 = lane & 15;
  // staging: lane covers row r8=(lane>>3), LDS chunk (lane&7); source chunk XOR'd by row
  int r8   = lane>>3;
  int srow = wv*32 + r8;
  int scol = (((lane&7) ^ r8) << 3);          // shorts, inverse-swizzled global column
  f32x4 acc[4][4];
  #pragma unroll
  for (int i=0;i<4;i++)
    #pragma unroll
    for (int j=0;j<4;j++) acc[i][j] = (f32x4){0.f,0.f,0.f,0.f};

  for (int k0=0; k0<K; k0+=64) {
    #pragma unroll
    for (int i=0;i<4;i++){
      gload_lds16(A  + (size_t)(mb+srow+i*8)*lda + k0 + scol, &As[(wv*32+i*8)*64 + lane*8]);
      gload_lds16(Bm + (size_t)(nb+srow+i*8)*ldb + k0 + scol, &Bs[(wv*32+i*8)*64 + lane*8]);
    }
    __syncthreads();
    #pragma unroll
    for (int ks=0; ks<2; ks++){
      int kb = ks<<5;
      s16x8 fa[4], fb[4];
      #pragma unroll
      for (int mi=0;mi<4;mi++){
        int row = wm*64+mi*16+r16;
        union { uint64_t q[2]; s16x8 v; } u;
        u.q[0] = *(const uint64_t*)&As[lds_swz(row, kb+g4)];
        u.q[1] = *(const uint64_t*)&As[lds_swz(row, kb+g4+16)];
        fa[mi] = u.v;
      }
      #pragma unroll
      for (int ni=0;ni<4;ni++){
        int row = wn*64+ni*16+r16;
        union { uint64_t q[2]; s16x8 v; } u;
        u.q[0] = *(const uint64_t*)&Bs[lds_swz(row, kb+g4)];
        u.q[1] = *(const uint64_t*)&Bs[lds_swz(row, kb+g4+16)];
        fb[ni] = u.v;
      }
      #pragma unroll
      for (int mi=0;mi<4;mi++)
        #pragma unroll
        for (int ni=0;ni<4;ni++)
          acc[mi][ni] = __builtin_amdgcn_mfma_f32_16x16x32_bf16(fa[mi], fb[ni], acc[mi][ni], 0,0,0);
    }
    __syncthreads();
  }
  #pragma unroll
  for (int mi=0;mi<4;mi++){
    #pragma unroll
    for (int ni=0;ni<4;ni++){
      #pragma unroll
      for (int rr=0;rr<4;rr++){
        int row = mb + wm*64 + mi*16 + g4 + rr;
        int col = nb + wn*64 + ni*16 + r16;
        float v = acc[mi][ni][rr];
        if constexpr (EPI == E_GELU_BF16){
          v += bias[col];
          oH[(size_t)row*ldo + col] = f2bf(gelu_f(v));
        } else if constexpr (EPI == E_BF16){
          if (bias) v += bias[col];
          if (oH2 && col >= 1024) oH2[(size_t)row*1024 + col - 1024] = f2bf(v);
          else                    oH [(size_t)row*ldo  + col] = f2bf(v);
        } else if constexpr (EPI == E_F32){
          oF[(size_t)row*ldo + col] = v;
        } else { // E_MOE
          size_t o = (size_t)row*ldo + col;
          if (bias) v += bias[col];
          float w = wfull[(size_t)row*8 + ecol];
          float base = resid ? resid[o] : oF[o];
          oF[o] = base + w*v;
        }
      }
    }
  }
}

extern "C" void kernel_launch(void* const* d_in, const int* in_sizes, int n_in,
                              void* d_out, int out_size, void* d_ws, size_t ws_size,
                              hipStream_t stream)
{
  (void)in_sizes; (void)n_in; (void)out_size;
  const float* x      = (const float*)d_in[0];
  const float* ln_g   = (const float*)d_in[1];
  const float* ln_b   = (const float*)d_in[2];
  const float* gate_w = (const float*)d_in[3];
  const float* ent_w  = (const float*)d_in[4];
  const float* ent_b  = (const float*)d_in[5];
  const float* temp   = (const float*)d_in[6];
  const float* cin_w  = (const float*)d_in[7];
  const float* cin_b  = (const float*)d_in[8];
  const float* ck     = (const float*)d_in[9];
  const float* ck_b   = (const float*)d_in[10];
  const float* cout_w = (const float*)d_in[11];
  const float* cout_b = (const float*)d_in[12];
  const float* m_in   = (const float*)d_in[13];
  const float* m_cw   = (const float*)d_in[14];
  const float* m_cb   = (const float*)d_in[15];
  const float* m_xp   = (const float*)d_in[16];
  const float* m_dtw  = (const float*)d_in[17];
  const float* m_dtb  = (const float*)d_in[18];
  const float* m_alog = (const float*)d_in[19];
  const float* m_Dd   = (const float*)d_in[20];
  const float* m_op   = (const float*)d_in[21];
  float* out = (float*)d_out;
  char* ws = (char*)d_ws;

  size_t off = 0;
  auto alloc = [&](size_t bytes)->size_t{
    size_t r = off; off += (bytes + 4095) & ~(size_t)4095; return r;
  };
  size_t o_xnH  = alloc((size_t)BT_*DM*2);
  size_t o_wf   = alloc((size_t)BT_*8*4);
  size_t o_st   = alloc(4096);
  size_t o_wCI  = alloc((size_t)4*DIN_*DM*2);
  size_t o_wCO  = alloc((size_t)4*DM*DIN_*2);
  size_t o_wIP  = alloc((size_t)4*2048*DM*2);
  size_t o_wXP  = alloc((size_t)4*128*DIN_*2);
  size_t o_wOP  = alloc((size_t)4*DM*DIN_*2);
  size_t o_A0   = alloc((size_t)BT_*DIN_*2);   // u_raw / conv H1 / y
  size_t o_A1   = alloc((size_t)BT_*DIN_*2);   // z
  size_t o_A3   = alloc((size_t)BT_*DIN_*2);   // u' / conv H2
  size_t o_A4   = alloc((size_t)BT_*128*4);    // dbc f32
  size_t o_xnT  = alloc((size_t)BT_*DM*4);     // f32 xn transposed (DM, BT)
  size_t need = off;

  if (ws_size < need){
    diag_k<<<1,1,0,stream>>>(out, (float)(ws_size >> 20));
    return;
  }

  unsigned short* xnH  = (unsigned short*)(ws + o_xnH);
  float*          xnT  = (float*)(ws + o_xnT);
  float*          wfull= (float*)(ws + o_wf);
  float*          entP = (float*)(ws + o_st);
  float*          gtpe = (float*)(ws + o_st + 512);
  float*          gavg = (float*)(ws + o_st + 544);
  unsigned short* wtCI = (unsigned short*)(ws + o_wCI);
  unsigned short* wtCO = (unsigned short*)(ws + o_wCO);
  unsigned short* wtIP = (unsigned short*)(ws + o_wIP);
  unsigned short* wtXP = (unsigned short*)(ws + o_wXP);
  unsigned short* wtOP = (unsigned short*)(ws + o_wOP);
  unsigned short* a0H  = (unsigned short*)(ws + o_A0);
  unsigned short* a1H  = (unsigned short*)(ws + o_A1);
  unsigned short* a3H  = (unsigned short*)(ws + o_A3);
  float*          a4F  = (float*)(ws + o_A4);

  hipMemsetAsync(ws + o_st, 0, 4096, stream);

  transpose_cvt<<<dim3(32,16,4),256,0,stream>>>(cin_w,  wtCI, 512, 1024, 1024);
  transpose_cvt<<<dim3(16,32,4),256,0,stream>>>(cout_w, wtCO, 1024, 512, 512);
  transpose_cvt<<<dim3(64,16,4),256,0,stream>>>(m_in,   wtIP, 512, 2048, 2048);
  transpose_cvt<<<dim3( 4,32,4),256,0,stream>>>(m_xp,   wtXP, 1024, 64, 128);
  transpose_cvt<<<dim3(16,32,4),256,0,stream>>>(m_op,   wtOP, 1024, 512, 512);

  ln_kernel<<<BT_/64,256,0,stream>>>(x, ln_g, ln_b, xnT, xnH);
  entropy_kernel<<<Bb*NW*512/4,256,0,stream>>>(xnT, entP);
  gating_kernel<<<BT_/64,256,0,stream>>>(xnT, gate_w, ent_w, ent_b, temp, entP, wfull, gtpe, gavg);

  // conv experts (0..3)
  for (int e=0;e<4;e++){
    gemm_k<E_GELU_BF16><<<dim3(8,128),256,0,stream>>>(
        xnH, DM, wtCI + (size_t)e*DIN_*DM, DM, DM,
        cin_b + (size_t)e*DIN_, nullptr, a0H, DIN_, nullptr, 0, nullptr, nullptr);
    dwconv7_gelu<<<BT_*DIN_/8/256,256,0,stream>>>(a0H, ck + (size_t)e*DIN_*7, ck_b + (size_t)e*DIN_, a3H);
    gemm_k<E_MOE><<<dim3(4,128),256,0,stream>>>(
        a3H, DIN_, wtCO + (size_t)e*DM*DIN_, DIN_, DIN_,
        cout_b + (size_t)e*DM, out, nullptr, DM, wfull, e, (e==0)? x : nullptr, nullptr);
  }

  // mamba experts (4..7)
  for (int e=0;e<4;e++){
    gemm_k<E_BF16><<<dim3(16,128),256,0,stream>>>(
        xnH, DM, wtIP + (size_t)e*2048*DM, DM, DM,
        nullptr, nullptr, a0H, DIN_, nullptr, 0, nullptr, a1H);            // u_raw + z split
    dwconv4_silu<<<BT_*DIN_/8/256,256,0,stream>>>(a0H, m_cw + (size_t)e*DIN_*4, m_cb + (size_t)e*DIN_, a3H);
    gemm_k<E_F32><<<dim3(1,128),256,0,stream>>>(
        a3H, DIN_, wtXP + (size_t)e*128*DIN_, DIN_, DIN_,
        nullptr, a4F, nullptr, 128, nullptr, 0, nullptr, nullptr);         // dbc
    scan_k<<<512,256,0,stream>>>(a4F, a3H, a1H,
        m_dtw + (size_t)e*32*DIN_, m_dtb + (size_t)e*DIN_,
        m_alog + (size_t)e*DIN_*DSTATE_, m_Dd + (size_t)e*DIN_, a0H);      // y -> a0H
    gemm_k<E_MOE><<<dim3(4,128),256,0,stream>>>(
        a0H, DIN_, wtOP + (size_t)e*DM*DIN_, DIN_, DIN_,
        nullptr, out, nullptr, DM, wfull, 4+e, nullptr, nullptr);
  }

  aux_kernel<<<1,1,0,stream>>>(gtpe, gavg, out);
}